// Round 2
// baseline (501.277 us; speedup 1.0000x reference)
//
#include <hip/hip_runtime.h>
#include <hip/hip_bf16.h>
#include <math.h>

#define NN 2304      // H*W = 48*48
#define ROWSZ 4608   // B*N
#define SZ (ROWSZ*256)

__device__ __forceinline__ float bf2f(unsigned short u) {
    return __uint_as_float(((unsigned int)u) << 16);
}
__device__ __forceinline__ unsigned short f2bf(float f) {
    unsigned int u = __float_as_uint(f);
    u += 0x7FFFu + ((u >> 16) & 1u);   // round-to-nearest-even
    return (unsigned short)(u >> 16);
}

template<int F32>
__device__ __forceinline__ float ldin(const void* p, int i) {
    if constexpr (F32) return ((const float*)p)[i];
    else return bf2f(((const unsigned short*)p)[i]);
}

// ---------------- dtype detector -------------------------------------------
// bf16 array: low 16 bits of each u32 word are a sane bf16 (exp in [87,167]
// for N(0,1)-scale data). f32 array: low 16 bits are mantissa garbage
// (~68% outside the band). Count over 256 words; >=32 outside -> f32.
__global__ void detect_kernel(const unsigned int* __restrict__ x, int* __restrict__ flag) {
    int t = threadIdx.x;
    int cnt = 0;
    for (int i = t; i < 256; i += 64) {
        unsigned int e = (x[i] >> 7) & 0xFFu;
        cnt += (e < 87u || e > 167u) ? 1 : 0;
    }
    #pragma unroll
    for (int o = 32; o; o >>= 1) cnt += __shfl_down(cnt, o);
    if (t == 0) *flag = (cnt >= 32) ? 1 : 0;
}

// ---------------- QKV projection + fused RoPE + k-scaling ------------------
// grid 288, block 256: 16 rows/block, thread t owns output column t.
template<int F32>
__global__ __launch_bounds__(256) void qkv_kernel(
    const void* __restrict__ x,
    const void* __restrict__ Wq, const void* __restrict__ bq,
    const void* __restrict__ Wk, const void* __restrict__ bk,
    const void* __restrict__ Wv, const void* __restrict__ bv,
    const int* __restrict__ flag,
    unsigned short* __restrict__ q, unsigned short* __restrict__ k,
    unsigned short* __restrict__ v)
{
    if (*flag != F32) return;
    __shared__ float xs[16*256];
    const int t = threadIdx.x;
    const int row0 = blockIdx.x * 16;
    #pragma unroll
    for (int pass = 0; pass < 2; ++pass) {
        int e = pass*2048 + t*8;
        if constexpr (F32) {
            const float* xp = (const float*)x + row0*256 + e;
            float4 a0 = *reinterpret_cast<const float4*>(xp);
            float4 a1 = *reinterpret_cast<const float4*>(xp + 4);
            *reinterpret_cast<float4*>(&xs[e])   = a0;
            *reinterpret_cast<float4*>(&xs[e+4]) = a1;
        } else {
            const unsigned short* xp = (const unsigned short*)x + row0*256 + e;
            uint4 raw = *reinterpret_cast<const uint4*>(xp);
            const unsigned short* us = reinterpret_cast<const unsigned short*>(&raw);
            #pragma unroll
            for (int j = 0; j < 8; ++j) xs[e + j] = bf2f(us[j]);
        }
    }
    __syncthreads();
    float aq[16], ak[16], av[16];
    const float bqv = ldin<F32>(bq, t), bkv = ldin<F32>(bk, t), bvv = ldin<F32>(bv, t);
    #pragma unroll
    for (int r = 0; r < 16; ++r) { aq[r]=bqv; ak[r]=bkv; av[r]=bvv; }
    for (int i0 = 0; i0 < 256; i0 += 4) {
        float wq[4], wk[4], wv[4];
        #pragma unroll
        for (int ii = 0; ii < 4; ++ii) {
            int idx = (i0+ii)*256 + t;
            wq[ii]=ldin<F32>(Wq,idx); wk[ii]=ldin<F32>(Wk,idx); wv[ii]=ldin<F32>(Wv,idx);
        }
        #pragma unroll
        for (int r = 0; r < 16; ++r) {
            float4 xv = *reinterpret_cast<const float4*>(&xs[r*256 + i0]);
            aq[r] = fmaf(xv.w,wq[3], fmaf(xv.z,wq[2], fmaf(xv.y,wq[1], fmaf(xv.x,wq[0], aq[r]))));
            ak[r] = fmaf(xv.w,wk[3], fmaf(xv.z,wk[2], fmaf(xv.y,wk[1], fmaf(xv.x,wk[0], ak[r]))));
            av[r] = fmaf(xv.w,wv[3], fmaf(xv.z,wv[2], fmaf(xv.y,wv[1], fmaf(xv.x,wv[0], av[r]))));
        }
    }
    // fused RoPE: column t -> head h=t>>5, dim dd=t&31, pair j=dd>>1
    const float scaling = 0.17677669529663687f;  // 32^-0.5
    const int j = (t & 31) >> 1;
    const float ang = exp2f((float)j * (-0.8858474919699633f)); // 10000^(-j/15)
    const bool odd = t & 1;
    #pragma unroll
    for (int r = 0; r < 16; ++r) {
        int bn = row0 + r;
        int n = bn >= NN ? bn - NN : bn;
        float sv, cv;
        sincosf((float)n * ang, &sv, &cv);
        float qp = __shfl_xor(aq[r], 1);
        float kp = __shfl_xor(ak[r], 1);
        float qv = odd ? fmaf(aq[r], cv,  qp*sv) : fmaf(aq[r], cv, -qp*sv);
        float kv = odd ? fmaf(ak[r], cv,  kp*sv) : fmaf(ak[r], cv, -kp*sv);
        int idx = bn*256 + t;
        q[idx] = f2bf(qv);
        k[idx] = f2bf(kv * scaling);
        v[idx] = f2bf(av[r]);
    }
}

// ---------------- depthwise 5x5 SAME conv on v (+ bias) --------------------
template<int F32>
__global__ __launch_bounds__(256) void lepe_kernel(const unsigned short* __restrict__ v,
    const void* __restrict__ w, const void* __restrict__ wb,
    const int* __restrict__ flag, unsigned short* __restrict__ lepe)
{
    if (*flag != F32) return;
    int c = threadIdx.x;
    int pos = blockIdx.x;                // b*2304 + y*48 + x
    int b  = pos >= NN ? 1 : 0;
    int yx = pos - b*NN;
    int y  = (yx*21846) >> 20;           // yx/48 exact for yx<32768
    int xx = yx - y*48;
    float acc = ldin<F32>(wb, c);
    #pragma unroll
    for (int ky = 0; ky < 5; ++ky) {
        int yy = y + ky - 2;
        if ((unsigned)yy >= 48u) continue;
        #pragma unroll
        for (int kx = 0; kx < 5; ++kx) {
            int xc = xx + kx - 2;
            if ((unsigned)xc >= 48u) continue;
            acc = fmaf(bf2f(v[((b*NN + yy*48 + xc)<<8) + c]), ldin<F32>(w, c*25 + ky*5 + kx), acc);
        }
    }
    lepe[(pos<<8) + c] = f2bf(acc);
}

// ---------------- flash attention with decay mask --------------------------
// grid (36, 16): 64 q-rows per block for one (b,h); 256 thr = 4 phases/row
__global__ __launch_bounds__(256) void attn_kernel(
    const unsigned short* __restrict__ q, const unsigned short* __restrict__ k,
    const unsigned short* __restrict__ v, unsigned short* __restrict__ o)
{
    __shared__ float lds[8704];          // K/V tiles (2*64*36), reused for reduce (256*34)
    __shared__ int kyx[128];
    float* Ks = lds;
    float* Vs = lds + 64*36;
    const int t = threadIdx.x;
    const int bh = blockIdx.y;
    const int b = bh >> 3, h = bh & 7;
    const int r = t >> 2, p = t & 3;
    const int lc = p*8;
    const int nq = blockIdx.x*64 + r;
    const int yq = (nq*21846) >> 20;
    const int xq = nq - yq*48;
    const float decay = logf(1.0f - exp2f(-1.0f - 0.375f*(float)h));
    const unsigned short* qrow = q + (b*NN + nq)*256 + h*32;
    float qreg[32];
    #pragma unroll
    for (int d0 = 0; d0 < 32; d0 += 8) {
        uint4 raw = *reinterpret_cast<const uint4*>(qrow + d0);
        const unsigned short* us = reinterpret_cast<const unsigned short*>(&raw);
        #pragma unroll
        for (int jj = 0; jj < 8; ++jj) qreg[d0+jj] = bf2f(us[jj]);
    }
    float m = -INFINITY, l = 0.0f;
    float acc[32];
    #pragma unroll
    for (int d = 0; d < 32; ++d) acc[d] = 0.0f;
    const unsigned short* kb = k + (size_t)(b*NN)*256 + h*32;
    const unsigned short* vb = v + (size_t)(b*NN)*256 + h*32;
    for (int kt = 0; kt < 36; ++kt) {
        __syncthreads();
        {
            const int nk = kt*64 + r;
            uint4 kraw = *reinterpret_cast<const uint4*>(kb + nk*256 + lc);
            uint4 vraw = *reinterpret_cast<const uint4*>(vb + nk*256 + lc);
            const unsigned short* ku = reinterpret_cast<const unsigned short*>(&kraw);
            const unsigned short* vu = reinterpret_cast<const unsigned short*>(&vraw);
            float4 k0 = make_float4(bf2f(ku[0]), bf2f(ku[1]), bf2f(ku[2]), bf2f(ku[3]));
            float4 k1 = make_float4(bf2f(ku[4]), bf2f(ku[5]), bf2f(ku[6]), bf2f(ku[7]));
            float4 v0 = make_float4(bf2f(vu[0]), bf2f(vu[1]), bf2f(vu[2]), bf2f(vu[3]));
            float4 v1 = make_float4(bf2f(vu[4]), bf2f(vu[5]), bf2f(vu[6]), bf2f(vu[7]));
            *reinterpret_cast<float4*>(&Ks[r*36+lc])   = k0;
            *reinterpret_cast<float4*>(&Ks[r*36+lc+4]) = k1;
            *reinterpret_cast<float4*>(&Vs[r*36+lc])   = v0;
            *reinterpret_cast<float4*>(&Vs[r*36+lc+4]) = v1;
            if (t < 64) {
                int n2 = kt*64 + t;
                int yy = (n2*21846) >> 20;
                kyx[t] = yy;
                kyx[64+t] = n2 - yy*48;
            }
        }
        __syncthreads();
        float s[16];
        #pragma unroll
        for (int i = 0; i < 16; ++i) {
            const int c = i*4 + p;
            const float* kr_ = &Ks[c*36];
            float sv = 0.0f;
            #pragma unroll
            for (int d0 = 0; d0 < 32; d0 += 4) {
                float4 kk = *reinterpret_cast<const float4*>(kr_ + d0);
                sv = fmaf(kk.x, qreg[d0],   sv);
                sv = fmaf(kk.y, qreg[d0+1], sv);
                sv = fmaf(kk.z, qreg[d0+2], sv);
                sv = fmaf(kk.w, qreg[d0+3], sv);
            }
            int dy = yq - kyx[c];     dy = dy < 0 ? -dy : dy;
            int dx = xq - kyx[64+c];  dx = dx < 0 ? -dx : dx;
            s[i] = fmaf(decay, (float)(dy+dx), sv);
        }
        float tm = s[0];
        #pragma unroll
        for (int i = 1; i < 16; ++i) tm = fmaxf(tm, s[i]);
        float mnew = fmaxf(m, tm);
        float scale = __expf(m - mnew);    // first tile: exp(-inf)=0
        l *= scale;
        #pragma unroll
        for (int d = 0; d < 32; ++d) acc[d] *= scale;
        m = mnew;
        #pragma unroll
        for (int i = 0; i < 16; ++i) {
            const int c = i*4 + p;
            float pv = __expf(s[i] - m);
            l += pv;
            const float* vr = &Vs[c*36];
            #pragma unroll
            for (int d0 = 0; d0 < 32; d0 += 4) {
                float4 vv = *reinterpret_cast<const float4*>(vr + d0);
                acc[d0]   = fmaf(pv, vv.x, acc[d0]);
                acc[d0+1] = fmaf(pv, vv.y, acc[d0+1]);
                acc[d0+2] = fmaf(pv, vv.z, acc[d0+2]);
                acc[d0+3] = fmaf(pv, vv.w, acc[d0+3]);
            }
        }
    }
    // combine the 4 phases of each row
    __syncthreads();
    float* myred = lds + (r*4 + p)*34;
    #pragma unroll
    for (int d = 0; d < 32; ++d) myred[d] = acc[d];
    myred[32] = m; myred[33] = l;
    __syncthreads();
    const float* rr = lds + r*136;
    float m0 = rr[32], m1 = rr[66], m2 = rr[100], m3 = rr[134];
    float M = fmaxf(fmaxf(m0, m1), fmaxf(m2, m3));
    float e0 = __expf(m0 - M), e1 = __expf(m1 - M), e2 = __expf(m2 - M), e3 = __expf(m3 - M);
    float L = e0*rr[33] + e1*rr[67] + e2*rr[101] + e3*rr[135];
    float invL = 1.0f / L;
    unsigned short* og = o + (size_t)(b*NN + nq)*256 + h*32 + p*8;
    #pragma unroll
    for (int d = 0; d < 8; ++d) {
        int dd = p*8 + d;
        float val = e0*rr[dd] + e1*rr[34+dd] + e2*rr[68+dd] + e3*rr[102+dd];
        og[d] = f2bf(val * invL);
    }
}

// ---------------- (attn_out + lepe) @ Wo + bo -> out -----------------------
template<int F32>
__global__ __launch_bounds__(256) void out_kernel(
    const unsigned short* __restrict__ o, const unsigned short* __restrict__ lp,
    const void* __restrict__ Wo, const void* __restrict__ bo,
    const int* __restrict__ flag, void* __restrict__ out)
{
    if (*flag != F32) return;
    __shared__ float as[16*256];
    const int t = threadIdx.x;
    const int row0 = blockIdx.x * 16;
    #pragma unroll
    for (int pass = 0; pass < 2; ++pass) {
        int e = pass*2048 + t*8;
        uint4 ua = *reinterpret_cast<const uint4*>(o  + row0*256 + e);
        uint4 ub = *reinterpret_cast<const uint4*>(lp + row0*256 + e);
        const unsigned short* au = reinterpret_cast<const unsigned short*>(&ua);
        const unsigned short* bu = reinterpret_cast<const unsigned short*>(&ub);
        #pragma unroll
        for (int jj = 0; jj < 8; ++jj) as[e+jj] = bf2f(au[jj]) + bf2f(bu[jj]);
    }
    __syncthreads();
    float a[16];
    const float bv = ldin<F32>(bo, t);
    #pragma unroll
    for (int r = 0; r < 16; ++r) a[r] = bv;
    for (int i0 = 0; i0 < 256; i0 += 4) {
        float w0 = ldin<F32>(Wo, (i0+0)*256 + t);
        float w1 = ldin<F32>(Wo, (i0+1)*256 + t);
        float w2 = ldin<F32>(Wo, (i0+2)*256 + t);
        float w3 = ldin<F32>(Wo, (i0+3)*256 + t);
        #pragma unroll
        for (int r = 0; r < 16; ++r) {
            float4 xv = *reinterpret_cast<const float4*>(&as[r*256 + i0]);
            a[r] = fmaf(xv.w,w3, fmaf(xv.z,w2, fmaf(xv.y,w1, fmaf(xv.x,w0, a[r]))));
        }
    }
    #pragma unroll
    for (int r = 0; r < 16; ++r) {
        int idx = (row0+r)*256 + t;
        if constexpr (F32) ((float*)out)[idx] = a[r];
        else ((unsigned short*)out)[idx] = f2bf(a[r]);
    }
}

extern "C" void kernel_launch(void* const* d_in, const int* in_sizes, int n_in,
                              void* d_out, int out_size, void* d_ws, size_t ws_size,
                              hipStream_t stream)
{
    const void* x  = d_in[0];
    const void* Wq = d_in[1];
    const void* bq = d_in[2];
    const void* Wk = d_in[3];
    const void* bk = d_in[4];
    const void* Wv = d_in[5];
    const void* bv = d_in[6];
    const void* lw = d_in[7];
    const void* lb = d_in[8];
    const void* Wo = d_in[9];
    const void* bo = d_in[10];

    // ws layout: [flag (256B)] [q][k][v][o][lp] each SZ bf16 (2.36 MB) = 11.3 MB total
    int* flag = (int*)d_ws;
    unsigned short* qb = (unsigned short*)((char*)d_ws + 256);
    unsigned short* kbuf = qb + (size_t)SZ;
    unsigned short* vbuf = kbuf + (size_t)SZ;
    unsigned short* obuf = vbuf + (size_t)SZ;
    unsigned short* lbuf = obuf + (size_t)SZ;

    detect_kernel<<<1, 64, 0, stream>>>((const unsigned int*)x, flag);
    qkv_kernel<0><<<288, 256, 0, stream>>>(x, Wq, bq, Wk, bk, Wv, bv, flag, qb, kbuf, vbuf);
    qkv_kernel<1><<<288, 256, 0, stream>>>(x, Wq, bq, Wk, bk, Wv, bv, flag, qb, kbuf, vbuf);
    lepe_kernel<0><<<4608, 256, 0, stream>>>(vbuf, lw, lb, flag, lbuf);
    lepe_kernel<1><<<4608, 256, 0, stream>>>(vbuf, lw, lb, flag, lbuf);
    attn_kernel<<<dim3(36, 16), 256, 0, stream>>>(qb, kbuf, vbuf, obuf);
    out_kernel<0><<<288, 256, 0, stream>>>(obuf, lbuf, Wo, bo, flag, d_out);
    out_kernel<1><<<288, 256, 0, stream>>>(obuf, lbuf, Wo, bo, flag, d_out);
}

// Round 3
// 266.797 us; speedup vs baseline: 1.8789x; 1.8789x over previous
//
#include <hip/hip_runtime.h>
#include <hip/hip_bf16.h>
#include <math.h>

#define NN 2304      // H*W = 48*48
#define ROWSZ 4608   // B*N
#define SZ (ROWSZ*256)

typedef __attribute__((ext_vector_type(8))) short short8;
typedef __attribute__((ext_vector_type(4))) float f32x4;

__device__ __forceinline__ float bf2f(unsigned short u) {
    return __uint_as_float(((unsigned int)u) << 16);
}
__device__ __forceinline__ unsigned short f2bf(float f) {
    unsigned int u = __float_as_uint(f);
    u += 0x7FFFu + ((u >> 16) & 1u);   // round-to-nearest-even
    return (unsigned short)(u >> 16);
}
__device__ __forceinline__ unsigned int pack_bf2(float a, float b) {
    return (unsigned int)f2bf(a) | ((unsigned int)f2bf(b) << 16);
}

template<int F32>
__device__ __forceinline__ float ldin(const void* p, int i) {
    if constexpr (F32) return ((const float*)p)[i];
    else return bf2f(((const unsigned short*)p)[i]);
}

// ---------------- dtype detector -------------------------------------------
__global__ void detect_kernel(const unsigned int* __restrict__ x, int* __restrict__ flag) {
    int t = threadIdx.x;
    int cnt = 0;
    for (int i = t; i < 256; i += 64) {
        unsigned int e = (x[i] >> 7) & 0xFFu;
        cnt += (e < 87u || e > 167u) ? 1 : 0;
    }
    #pragma unroll
    for (int o = 32; o; o >>= 1) cnt += __shfl_down(cnt, o);
    if (t == 0) *flag = (cnt >= 32) ? 1 : 0;
}

// ---------------- QKV projection + fused RoPE + k-scaling + vT -------------
// grid (288,3): 16 rows/block, blockIdx.y selects matrix {q,k,v}
template<int F32>
__global__ __launch_bounds__(256) void qkv_kernel(
    const void* __restrict__ x,
    const void* __restrict__ Wq, const void* __restrict__ bq,
    const void* __restrict__ Wk, const void* __restrict__ bk,
    const void* __restrict__ Wv, const void* __restrict__ bv,
    const int* __restrict__ flag,
    unsigned short* __restrict__ q, unsigned short* __restrict__ k,
    unsigned short* __restrict__ v, unsigned short* __restrict__ vT)
{
    if (*flag != F32) return;
    __shared__ float xs[16*256];
    const int t = threadIdx.x;
    const int by = blockIdx.y;
    const int row0 = blockIdx.x * 16;
    #pragma unroll
    for (int pass = 0; pass < 2; ++pass) {
        int e = pass*2048 + t*8;
        if constexpr (F32) {
            const float* xp = (const float*)x + row0*256 + e;
            float4 a0 = *reinterpret_cast<const float4*>(xp);
            float4 a1 = *reinterpret_cast<const float4*>(xp + 4);
            *reinterpret_cast<float4*>(&xs[e])   = a0;
            *reinterpret_cast<float4*>(&xs[e+4]) = a1;
        } else {
            const unsigned short* xp = (const unsigned short*)x + row0*256 + e;
            uint4 raw = *reinterpret_cast<const uint4*>(xp);
            const unsigned short* us = reinterpret_cast<const unsigned short*>(&raw);
            #pragma unroll
            for (int j = 0; j < 8; ++j) xs[e + j] = bf2f(us[j]);
        }
    }
    __syncthreads();
    const void* Wsel = (by == 0) ? Wq : (by == 1) ? Wk : Wv;
    const void* bsel = (by == 0) ? bq : (by == 1) ? bk : bv;
    float a[16];
    const float bv0 = ldin<F32>(bsel, t);
    #pragma unroll
    for (int r = 0; r < 16; ++r) a[r] = bv0;
    for (int i0 = 0; i0 < 256; i0 += 4) {
        float w0 = ldin<F32>(Wsel, (i0+0)*256 + t);
        float w1 = ldin<F32>(Wsel, (i0+1)*256 + t);
        float w2 = ldin<F32>(Wsel, (i0+2)*256 + t);
        float w3 = ldin<F32>(Wsel, (i0+3)*256 + t);
        #pragma unroll
        for (int r = 0; r < 16; ++r) {
            float4 xv = *reinterpret_cast<const float4*>(&xs[r*256 + i0]);
            a[r] = fmaf(xv.w,w3, fmaf(xv.z,w2, fmaf(xv.y,w1, fmaf(xv.x,w0, a[r]))));
        }
    }
    if (by == 2) {
        // v row-major + vT [bh][d][n]
        const int b = (row0 >= NN) ? 1 : 0;
        const int n0 = row0 - b*NN;
        const int h = t >> 5, d = t & 31;
        unsigned int vp[8];
        #pragma unroll
        for (int r = 0; r < 16; ++r) v[(row0 + r)*256 + t] = f2bf(a[r]);
        #pragma unroll
        for (int r = 0; r < 8; ++r) vp[r] = pack_bf2(a[2*r], a[2*r+1]);
        unsigned short* vt = vT + ((size_t)(b*8 + h)*32 + d)*NN + n0;
        *reinterpret_cast<uint4*>(vt)     = make_uint4(vp[0], vp[1], vp[2], vp[3]);
        *reinterpret_cast<uint4*>(vt + 8) = make_uint4(vp[4], vp[5], vp[6], vp[7]);
    } else {
        // RoPE: column t -> pair j=(t&31)>>1
        const float scaling = 0.17677669529663687f;  // 32^-0.5
        const int j = (t & 31) >> 1;
        const float ang = exp2f((float)j * (-0.8858474919699633f)); // 10000^(-j/15)
        const bool odd = t & 1;
        unsigned short* dst = (by == 0) ? q : k;
        const float mul = (by == 0) ? 1.0f : scaling;
        #pragma unroll
        for (int r = 0; r < 16; ++r) {
            int bn = row0 + r;
            int n = bn >= NN ? bn - NN : bn;
            float sv, cv;
            sincosf((float)n * ang, &sv, &cv);
            float ap = __shfl_xor(a[r], 1);
            float val = odd ? fmaf(a[r], cv, ap*sv) : fmaf(a[r], cv, -ap*sv);
            dst[bn*256 + t] = f2bf(val * mul);
        }
    }
}

// ---------------- depthwise 5x5 SAME conv on v (+ bias) --------------------
template<int F32>
__global__ __launch_bounds__(256) void lepe_kernel(const unsigned short* __restrict__ v,
    const void* __restrict__ w, const void* __restrict__ wb,
    const int* __restrict__ flag, unsigned short* __restrict__ lepe)
{
    if (*flag != F32) return;
    int c = threadIdx.x;
    int pos = blockIdx.x;                // b*2304 + y*48 + x
    int b  = pos >= NN ? 1 : 0;
    int yx = pos - b*NN;
    int y  = (yx*21846) >> 20;           // yx/48 exact
    int xx = yx - y*48;
    float acc = ldin<F32>(wb, c);
    #pragma unroll
    for (int ky = 0; ky < 5; ++ky) {
        int yy = y + ky - 2;
        if ((unsigned)yy >= 48u) continue;
        #pragma unroll
        for (int kx = 0; kx < 5; ++kx) {
            int xc = xx + kx - 2;
            if ((unsigned)xc >= 48u) continue;
            acc = fmaf(bf2f(v[((b*NN + yy*48 + xc)<<8) + c]), ldin<F32>(w, c*25 + ky*5 + kx), acc);
        }
    }
    lepe[(pos<<8) + c] = f2bf(acc);
}

// ---------------- MFMA flash attention with decay mask ---------------------
// grid (36,16), 256 thr = 4 waves; wave w: 16 q-rows; chunk = 64 kpos.
// S^T tiles: A=K (m=kpos), B=Q^T (n=q); PV: O^T = Vt * P^T.
__global__ __launch_bounds__(256) void attn_kernel(
    const unsigned short* __restrict__ q, const unsigned short* __restrict__ k,
    const unsigned short* __restrict__ vT, unsigned short* __restrict__ o)
{
    __shared__ char smem[17920];
    char* KsB = smem;                 // 64 rows * 80B (32 bf16 + pad)
    char* VtB = smem + 5120;          // 32 rows * 144B (64 bf16 + pad)
    const int t = threadIdx.x;
    const int w = t >> 6, lane = t & 63;
    const int q16 = lane & 15, quad = lane >> 4;
    char* PsB = smem + 9728 + w*2048; // per-wave P scratch, frag-ordered (2*1024B)
    const int bh = blockIdx.y, b = bh >> 3, h = bh & 7;
    const int q0 = blockIdx.x*64 + w*16;
    const int nq = q0 + q16;
    const int yq = (nq*21846) >> 20, xq = nq - yq*48;
    const float decay = logf(1.0f - exp2f(-1.0f - 0.375f*(float)h));
    short8 qfrag = *reinterpret_cast<const short8*>(q + ((size_t)(b*NN + nq))*256 + h*32 + quad*8);
    f32x4 acc0 = {0.f,0.f,0.f,0.f}, acc1 = {0.f,0.f,0.f,0.f};
    const f32x4 zero = {0.f,0.f,0.f,0.f};
    float m = -INFINITY, l = 0.0f;
    const unsigned short* kbase = k + (size_t)(b*NN)*256 + h*32;
    const unsigned short* vtb = vT + (size_t)bh*32*NN;
    const int skr = t >> 2, skp = t & 3;      // K staging: row, 16B-part
    const int svd = t >> 3, svp = t & 7;      // Vt staging: d, 16B-part
    const int psW = q16*16 + (quad & 1)*8;    // P write base within group
    const int qsh = quad >> 1;
    for (int kt = 0; kt < 36; ++kt) {
        __syncthreads();
        {
            uint4 kraw = *reinterpret_cast<const uint4*>(kbase + (kt*64 + skr)*256 + skp*8);
            uint4 vraw = *reinterpret_cast<const uint4*>(vtb + svd*NN + kt*64 + svp*8);
            *reinterpret_cast<uint4*>(KsB + skr*80 + skp*16) = kraw;
            *reinterpret_cast<uint4*>(VtB + svd*144 + svp*16) = vraw;
        }
        __syncthreads();
        // QK^T: 4 S^T tiles of [16 kpos x 16 q]
        f32x4 st[4];
        #pragma unroll
        for (int tt = 0; tt < 4; ++tt) {
            short8 kf = *reinterpret_cast<const short8*>(KsB + (tt*16 + q16)*80 + quad*16);
            st[tt] = __builtin_amdgcn_mfma_f32_16x16x32_bf16(kf, qfrag, zero, 0, 0, 0);
        }
        // decay mask + row max
        float mx = -INFINITY;
        #pragma unroll
        for (int tt = 0; tt < 4; ++tt) {
            #pragma unroll
            for (int r = 0; r < 4; ++r) {
                int kpos = kt*64 + tt*16 + quad*4 + r;
                int yk = (kpos*21846) >> 20;
                int xk = kpos - yk*48;
                int dist = __usad((unsigned)yq, (unsigned)yk, __usad((unsigned)xq, (unsigned)xk, 0u));
                float sv = fmaf(decay, (float)dist, st[tt][r]);
                st[tt][r] = sv;
                mx = fmaxf(mx, sv);
            }
        }
        mx = fmaxf(mx, __shfl_xor(mx, 16));
        mx = fmaxf(mx, __shfl_xor(mx, 32));
        float mn = fmaxf(m, mx);
        float alpha = __expf(m - mn);   // first chunk: exp(-inf)=0
        m = mn;
        float lsum = 0.0f;
        unsigned int pk[8];
        #pragma unroll
        for (int tt = 0; tt < 4; ++tt) {
            float p0 = __expf(st[tt][0] - mn);
            float p1 = __expf(st[tt][1] - mn);
            float p2 = __expf(st[tt][2] - mn);
            float p3 = __expf(st[tt][3] - mn);
            lsum += (p0 + p1) + (p2 + p3);
            pk[tt*2]   = __builtin_amdgcn_perm(__float_as_uint(p1), __float_as_uint(p0), 0x07060302);
            pk[tt*2+1] = __builtin_amdgcn_perm(__float_as_uint(p3), __float_as_uint(p2), 0x07060302);
        }
        lsum += __shfl_xor(lsum, 16);
        lsum += __shfl_xor(lsum, 32);
        l = l*alpha + lsum;
        #pragma unroll
        for (int r = 0; r < 4; ++r) { acc0[r] *= alpha; acc1[r] *= alpha; }
        // P -> LDS (frag order): value(q16, kp=tt*16+quad*4+r) at
        //   [kh=tt>>1][quadT=(tt*2+qsh)&3][q16][j=(quad&1)*4+r]
        #pragma unroll
        for (int tt = 0; tt < 4; ++tt) {
            uint2 pp; pp.x = pk[tt*2]; pp.y = pk[tt*2+1];
            *reinterpret_cast<uint2*>(PsB + (tt >> 1)*1024 + (((tt*2) + qsh) & 3)*256 + psW) = pp;
        }
        // PV: O^T += Vt * P^T  (two 32-kpos steps, two 16-d tiles)
        #pragma unroll
        for (int kh = 0; kh < 2; ++kh) {
            short8 pf = *reinterpret_cast<const short8*>(PsB + kh*1024 + lane*16);
            short8 v0 = *reinterpret_cast<const short8*>(VtB + q16*144 + kh*64 + quad*16);
            short8 v1 = *reinterpret_cast<const short8*>(VtB + (16 + q16)*144 + kh*64 + quad*16);
            acc0 = __builtin_amdgcn_mfma_f32_16x16x32_bf16(v0, pf, acc0, 0, 0, 0);
            acc1 = __builtin_amdgcn_mfma_f32_16x16x32_bf16(v1, pf, acc1, 0, 0, 0);
        }
    }
    float invl = 1.0f / l;
    // lane holds O^T[d = half*16 + quad*4 + r][q = nq]
    unsigned short* orow = o + ((size_t)(b*NN + nq))*256 + h*32;
    uint2 w0, w1;
    w0.x = pack_bf2(acc0[0]*invl, acc0[1]*invl);
    w0.y = pack_bf2(acc0[2]*invl, acc0[3]*invl);
    w1.x = pack_bf2(acc1[0]*invl, acc1[1]*invl);
    w1.y = pack_bf2(acc1[2]*invl, acc1[3]*invl);
    *reinterpret_cast<uint2*>(orow + quad*4)      = w0;
    *reinterpret_cast<uint2*>(orow + 16 + quad*4) = w1;
}

// ---------------- (attn_out + lepe) @ Wo + bo -> out -----------------------
// grid 576: 8 rows/block
template<int F32>
__global__ __launch_bounds__(256) void out_kernel(
    const unsigned short* __restrict__ o, const unsigned short* __restrict__ lp,
    const void* __restrict__ Wo, const void* __restrict__ bo,
    const int* __restrict__ flag, void* __restrict__ out)
{
    if (*flag != F32) return;
    __shared__ float as[8*256];
    const int t = threadIdx.x;
    const int row0 = blockIdx.x * 8;
    {
        int e = t*8;
        uint4 ua = *reinterpret_cast<const uint4*>(o  + row0*256 + e);
        uint4 ub = *reinterpret_cast<const uint4*>(lp + row0*256 + e);
        const unsigned short* au = reinterpret_cast<const unsigned short*>(&ua);
        const unsigned short* bu = reinterpret_cast<const unsigned short*>(&ub);
        #pragma unroll
        for (int jj = 0; jj < 8; ++jj) as[e+jj] = bf2f(au[jj]) + bf2f(bu[jj]);
    }
    __syncthreads();
    float a[8];
    const float bv = ldin<F32>(bo, t);
    #pragma unroll
    for (int r = 0; r < 8; ++r) a[r] = bv;
    for (int i0 = 0; i0 < 256; i0 += 4) {
        float w0 = ldin<F32>(Wo, (i0+0)*256 + t);
        float w1 = ldin<F32>(Wo, (i0+1)*256 + t);
        float w2 = ldin<F32>(Wo, (i0+2)*256 + t);
        float w3 = ldin<F32>(Wo, (i0+3)*256 + t);
        #pragma unroll
        for (int r = 0; r < 8; ++r) {
            float4 xv = *reinterpret_cast<const float4*>(&as[r*256 + i0]);
            a[r] = fmaf(xv.w,w3, fmaf(xv.z,w2, fmaf(xv.y,w1, fmaf(xv.x,w0, a[r]))));
        }
    }
    #pragma unroll
    for (int r = 0; r < 8; ++r) {
        int idx = (row0+r)*256 + t;
        if constexpr (F32) ((float*)out)[idx] = a[r];
        else ((unsigned short*)out)[idx] = f2bf(a[r]);
    }
}

extern "C" void kernel_launch(void* const* d_in, const int* in_sizes, int n_in,
                              void* d_out, int out_size, void* d_ws, size_t ws_size,
                              hipStream_t stream)
{
    const void* x  = d_in[0];
    const void* Wq = d_in[1];
    const void* bq = d_in[2];
    const void* Wk = d_in[3];
    const void* bk = d_in[4];
    const void* Wv = d_in[5];
    const void* bv = d_in[6];
    const void* lw = d_in[7];
    const void* lb = d_in[8];
    const void* Wo = d_in[9];
    const void* bo = d_in[10];

    // ws: [flag 256B][q][k][v][o][lp][vT] each SZ bf16 (2.36MB) = ~14.2MB
    int* flag = (int*)d_ws;
    unsigned short* qb   = (unsigned short*)((char*)d_ws + 256);
    unsigned short* kbuf = qb   + (size_t)SZ;
    unsigned short* vbuf = kbuf + (size_t)SZ;
    unsigned short* obuf = vbuf + (size_t)SZ;
    unsigned short* lbuf = obuf + (size_t)SZ;
    unsigned short* vtb  = lbuf + (size_t)SZ;

    detect_kernel<<<1, 64, 0, stream>>>((const unsigned int*)x, flag);
    qkv_kernel<0><<<dim3(288,3), 256, 0, stream>>>(x, Wq, bq, Wk, bk, Wv, bv, flag, qb, kbuf, vbuf, vtb);
    qkv_kernel<1><<<dim3(288,3), 256, 0, stream>>>(x, Wq, bq, Wk, bk, Wv, bv, flag, qb, kbuf, vbuf, vtb);
    lepe_kernel<0><<<4608, 256, 0, stream>>>(vbuf, lw, lb, flag, lbuf);
    lepe_kernel<1><<<4608, 256, 0, stream>>>(vbuf, lw, lb, flag, lbuf);
    attn_kernel<<<dim3(36, 16), 256, 0, stream>>>(qb, kbuf, vtb, obuf);
    out_kernel<0><<<576, 256, 0, stream>>>(obuf, lbuf, Wo, bo, flag, d_out);
    out_kernel<1><<<576, 256, 0, stream>>>(obuf, lbuf, Wo, bo, flag, d_out);
}